// Round 5
// baseline (1162.262 us; speedup 1.0000x reference)
//
#include <hip/hip_runtime.h>
#include <cstdint>
#include <cstddef>

typedef unsigned short u16;
typedef __bf16 bf16x8 __attribute__((ext_vector_type(8)));
typedef float f32x4 __attribute__((ext_vector_type(4)));

#define MAXDISP 48
#define HH 64
#define WW 128

// ---------- bf16 helpers ----------
__device__ __forceinline__ float bf2f(unsigned int x) {
    union { unsigned int i; float f; } c; c.i = x << 16; return c.f;
}
__device__ __forceinline__ float bf2f_hi(unsigned int x) {
    union { unsigned int i; float f; } c; c.i = x & 0xffff0000u; return c.f;
}
__device__ __forceinline__ u16 f2bf(float f) {
    union { float f; unsigned int i; } c; c.f = f;
    unsigned int x = c.i;
    return (u16)((x + 0x7fffu + ((x >> 16) & 1u)) >> 16);   // RNE
}

// ---------- weight transform: BN-fold + swizzle into MFMA B-fragment order ----------
// dst[tap][nt][kc][lane][j] bf16, tap=kd*3+kh, co=nt*16+(lane&15),
// k-chunk kc: CIN=64: kw=kc>>1, c=(kc&1)*32+(lane>>4)*8+j ; CIN=32: kw=kc, c=(lane>>4)*8+j
__global__ __launch_bounds__(256) void wfrag_kernel(
    const float* __restrict__ w, const float* __restrict__ gam,
    const float* __restrict__ bet, const float* __restrict__ mea,
    const float* __restrict__ var,
    u16* __restrict__ dst, float* __restrict__ bias, int CIN, int KC)
{
    int idx = blockIdx.x * 256 + threadIdx.x;
    int n = 9 * 2 * KC * 512;
    if (idx < n) {
        int j    = idx & 7;
        int lane = (idx >> 3) & 63;
        int t2   = idx >> 9;
        int kc   = t2 % KC;
        int t3   = t2 / KC;
        int nt   = t3 & 1;
        int tap  = t3 >> 1;
        int co   = nt * 16 + (lane & 15);
        int qq   = lane >> 4;
        int kw, c;
        if (CIN == 64) { kw = kc >> 1; c = (kc & 1) * 32 + qq * 8 + j; }
        else           { kw = kc;      c = qq * 8 + j; }
        int kd = tap / 3, kh = tap % 3;
        float inv = gam[co] * rsqrtf(var[co] + 1e-5f);
        dst[idx] = f2bf(w[((size_t)co * CIN + c) * 27 + kd * 9 + kh * 3 + kw] * inv);
    }
    if (blockIdx.x == 0 && threadIdx.x < 32) {
        int co = threadIdx.x;
        float inv = gam[co] * rsqrtf(var[co] + 1e-5f);
        bias[co] = bet[co] - mea[co] * inv;
    }
}

// ---------- cost volume, channel-last: vol[bl][d][h][w][c64] bf16 ----------
#define RS 334   // r_s row stride (u16): stride/2 odd -> 2-way-free b32 reads
__global__ __launch_bounds__(256) void vol_build_kernel(
    const float* __restrict__ lg, const float* __restrict__ rg,
    const float* __restrict__ lc, const float* __restrict__ rc,
    u16* __restrict__ vol, int b0)
{
    __shared__ u16 r_s[128 * RS];       // [w][0..319 rg | 320..331 rc]
    __shared__ u16 o_s[4 * 128 * 68];   // [dl][w][c64 +4 pad]

    int bi  = blockIdx.x;               // bl*128 + dh*64 + h
    int h   = bi & 63;
    int dh  = (bi >> 6) & 1;
    int bl  = bi >> 7;
    int b   = b0 + bl;
    int tid = threadIdx.x;
    int w    = tid & 127;
    int part = tid >> 7;

    for (int idx = tid; idx < 320 * 32; idx += 256) {
        int c = idx >> 5, w4 = (idx & 31) << 2;
        const float4 v = *(const float4*)(rg + (((size_t)b * 320 + c) * 64 + h) * 128 + w4);
        r_s[(w4 + 0) * RS + c] = f2bf(v.x);
        r_s[(w4 + 1) * RS + c] = f2bf(v.y);
        r_s[(w4 + 2) * RS + c] = f2bf(v.z);
        r_s[(w4 + 3) * RS + c] = f2bf(v.w);
    }
    for (int idx = tid; idx < 12 * 32; idx += 256) {
        int c = idx >> 5, w4 = (idx & 31) << 2;
        const float4 v = *(const float4*)(rc + (((size_t)b * 12 + c) * 64 + h) * 128 + w4);
        r_s[(w4 + 0) * RS + 320 + c] = f2bf(v.x);
        r_s[(w4 + 1) * RS + 320 + c] = f2bf(v.y);
        r_s[(w4 + 2) * RS + 320 + c] = f2bf(v.z);
        r_s[(w4 + 3) * RS + 320 + c] = f2bf(v.w);
    }
    u16 lcv[12];
    if (part == 0) {
#pragma unroll
        for (int k = 0; k < 12; k++)
            lcv[k] = f2bf(lc[(((size_t)b * 12 + k) * 64 + h) * 128 + w]);
    }
    __syncthreads();

    int d0 = dh * 24;
    for (int dc = 0; dc < 24; dc += 4) {
        // ---- corr channels: part0 g 0..19, part1 g 20..39 ----
        for (int gb = 0; gb < 5; gb++) {
            int g0 = part * 20 + gb * 4;
            float lv[4][8];
#pragma unroll
            for (int gg = 0; gg < 4; gg++)
#pragma unroll
                for (int j = 0; j < 8; j++)
                    lv[gg][j] = lg[(((size_t)b * 320 + (g0 + gg) * 8 + j) * 64 + h) * 128 + w];
#pragma unroll
            for (int dl = 0; dl < 4; dl++) {
                int d = d0 + dc + dl;
                union { u16 us[4]; uint2 u2; } pk;
                pk.us[0] = pk.us[1] = pk.us[2] = pk.us[3] = 0;
                if (w >= d) {
#pragma unroll
                    for (int gg = 0; gg < 4; gg++) {
                        float s = 0.f;
                        int base = (w - d) * RS + (g0 + gg) * 8;
#pragma unroll
                        for (int jj = 0; jj < 4; jj++) {
                            unsigned int uu = *(const unsigned int*)&r_s[base + jj * 2];
                            s += lv[gg][jj * 2]     * bf2f(uu & 0xffffu);
                            s += lv[gg][jj * 2 + 1] * bf2f_hi(uu);
                        }
                        pk.us[gg] = f2bf(s * 0.125f);
                    }
                }
                *(uint2*)&o_s[(dl * 128 + w) * 68 + g0] = pk.u2;
            }
        }
        // ---- concat channels ----
#pragma unroll
        for (int dl = 0; dl < 4; dl++) {
            int d = d0 + dc + dl;
            union { u16 us[12]; uint2 u2[3]; } z;
            if (part == 0) {
#pragma unroll
                for (int k = 0; k < 12; k++) z.us[k] = (w >= d) ? lcv[k] : (u16)0;
                u16* dst = &o_s[(dl * 128 + w) * 68 + 40];
                *(uint2*)(dst + 0) = z.u2[0];
                *(uint2*)(dst + 4) = z.u2[1];
                *(uint2*)(dst + 8) = z.u2[2];
            } else {
                if (w >= d) {
                    int base = (w - d) * RS + 320;
#pragma unroll
                    for (int k = 0; k < 12; k++) z.us[k] = r_s[base + k];
                } else {
#pragma unroll
                    for (int k = 0; k < 12; k++) z.us[k] = 0;
                }
                u16* dst = &o_s[(dl * 128 + w) * 68 + 52];
                *(uint2*)(dst + 0) = z.u2[0];
                *(uint2*)(dst + 4) = z.u2[1];
                *(uint2*)(dst + 8) = z.u2[2];
            }
        }
        __syncthreads();
        // ---- flush 4 d-slabs, coalesced ----
#pragma unroll
        for (int i = 0; i < 16; i++) {
            int idx = i * 256 + tid;            // [0,4096)
            int dl  = idx >> 10;
            int rem = idx & 1023;
            int ww  = rem >> 3, cg = rem & 7;
            const u16* sp = &o_s[(dl * 128 + ww) * 68 + cg * 8];
            uint2 lo = *(const uint2*)sp;
            uint2 hi = *(const uint2*)(sp + 4);
            uint4 ov = { lo.x, lo.y, hi.x, hi.y };
            int d = d0 + dc + dl;
            *(uint4*)(vol + ((((size_t)bl * 48 + d) * 64 + h) * 128 + ww) * 64 + cg * 8) = ov;
        }
        __syncthreads();
    }
}

// ---------- conv1: implicit-GEMM MFMA + XCD swizzle + static 9-tap prefetch pipeline ----------
// Fully-static unroll (no dynamic back-edges -> no spill). Per tap:
//   sync(A): prior reads done, prefetched loads drained (had full MFMA cluster to land)
//   ds_write st ; sync(B) ; issue tap t+1 loads (clamped addr) ; weights+MFMA if valid.
__global__ __launch_bounds__(256) void conv1_mfma_kernel(
    const u16* __restrict__ vol, const u16* __restrict__ wf,
    const float* __restrict__ bias, u16* __restrict__ x1)
{
    __shared__ u16 a_s[1170 * 8];   // chunk (wp*9+cg), wp in [0,130), cg in [0,8)

    int p  = blockIdx.x;
    int bi = (p & 7) * 768 + (p >> 3);   // 6144 = 8 XCDs * 768: contiguous chunk per XCD
    int h  = bi & 63;
    int t1 = bi >> 6;
    int d  = t1 % 48;
    int bl = t1 / 48;
    int tid  = threadIdx.x;
    int lane = tid & 63, wid = tid >> 6;
    int lm = lane & 15, q = lane >> 4;

    // zero halo rows once (stages write wp 1..128 only); first sync(A) covers visibility
    if (tid < 16) {
        uint4 z = { 0, 0, 0, 0 };
        int wp = (tid >> 3) ? 129 : 0;
        *(uint4*)&a_s[(wp * 9 + (tid & 7)) * 8] = z;
    }

    f32x4 acc[2][2];
#pragma unroll
    for (int i = 0; i < 2; i++)
#pragma unroll
        for (int j = 0; j < 2; j++) acc[i][j] = { 0.f, 0.f, 0.f, 0.f };

    const size_t blb = (size_t)bl * 48;
#define C1_PLANE(kd_, kh_) \
    (vol + (((blb + (size_t)min(max(d + (kd_) - 1, 0), 47)) * 64 + min(max(h + (kh_) - 1, 0), 63))) * 8192)

    uint4 st[4];
    {
        const u16* src = C1_PLANE(0, 0);
#pragma unroll
        for (int i = 0; i < 4; i++) st[i] = *(const uint4*)(src + (i * 256 + tid) * 8);
    }

#pragma unroll
    for (int kd = 0; kd < 3; kd++) {
#pragma unroll
        for (int kh = 0; kh < 3; kh++) {
            int tap = kd * 3 + kh;

            __syncthreads();                    // (A)
#pragma unroll
            for (int i = 0; i < 4; i++) {
                int idx = i * 256 + tid;        // [0,1024)
                *(uint4*)&a_s[(((idx >> 3) + 1) * 9 + (idx & 7)) * 8] = st[i];
            }
            __syncthreads();                    // (B)

            if (tap < 8) {                      // prefetch next tap (static indices)
                int nkd = (tap + 1) / 3, nkh = (tap + 1) % 3;
                const u16* src = C1_PLANE(nkd, nkh);
#pragma unroll
                for (int i = 0; i < 4; i++) st[i] = *(const uint4*)(src + (i * 256 + tid) * 8);
            }

            bool valid = (kd == 0 ? (d > 0) : (kd == 2 ? (d < 47) : true))
                      && (kh == 0 ? (h > 0) : (kh == 2 ? (h < 63) : true));
            if (valid) {
                bf16x8 bfr[2][6];
#pragma unroll
                for (int nt = 0; nt < 2; nt++)
#pragma unroll
                    for (int kc = 0; kc < 6; kc++)
                        bfr[nt][kc] = *(const bf16x8*)(wf + (((size_t)tap * 2 + nt) * 6 + kc) * 512 + lane * 8);

#pragma unroll
                for (int kc = 0; kc < 6; kc++) {
                    int kw = kc >> 1;
                    int cg = (kc & 1) * 4 + q;
#pragma unroll
                    for (int mt = 0; mt < 2; mt++) {
                        int wp = (wid * 2 + mt) * 16 + lm + kw;
                        bf16x8 afr = *(const bf16x8*)&a_s[(wp * 9 + cg) * 8];
                        acc[mt][0] = __builtin_amdgcn_mfma_f32_16x16x32_bf16(afr, bfr[0][kc], acc[mt][0], 0, 0, 0);
                        acc[mt][1] = __builtin_amdgcn_mfma_f32_16x16x32_bf16(afr, bfr[1][kc], acc[mt][1], 0, 0, 0);
                    }
                }
            }
        }
    }
#undef C1_PLANE

    // epilogue: D row=(lane>>4)*4+reg = w-offset, col=lane&15 = co-offset
    u16* xb = x1 + ((blb + d) * 64 + h) * 4096;
#pragma unroll
    for (int mt = 0; mt < 2; mt++)
#pragma unroll
        for (int nt = 0; nt < 2; nt++) {
            int co = nt * 16 + lm;
            float bs = bias[co];
#pragma unroll
            for (int r = 0; r < 4; r++) {
                int w = (wid * 2 + mt) * 16 + q * 4 + r;
                xb[w * 32 + co] = f2bf(fmaxf(acc[mt][nt][r] + bs, 0.f));
            }
        }
}

// ---------- conv2: same static prefetch pipeline, CIN=32 ----------
__global__ __launch_bounds__(256) void conv2_mfma_kernel(
    const u16* __restrict__ x1, const u16* __restrict__ wf,
    const float* __restrict__ bias, float* __restrict__ out, int b0)
{
    __shared__ u16 a_s[650 * 8];    // chunk (wp*5+cg), wp in [0,130), cg in [0,4)

    int p  = blockIdx.x;
    int bi = (p & 7) * 768 + (p >> 3);
    int h  = bi & 63;
    int t1 = bi >> 6;
    int d  = t1 % 48;
    int bl = t1 / 48;
    int tid  = threadIdx.x;
    int lane = tid & 63, wid = tid >> 6;
    int lm = lane & 15, q = lane >> 4;

    if (tid < 8) {
        uint4 z = { 0, 0, 0, 0 };
        int wp = (tid >> 2) ? 129 : 0;
        *(uint4*)&a_s[(wp * 5 + (tid & 3)) * 8] = z;
    }

    f32x4 acc[2][2];
#pragma unroll
    for (int i = 0; i < 2; i++)
#pragma unroll
        for (int j = 0; j < 2; j++) acc[i][j] = { 0.f, 0.f, 0.f, 0.f };

    const size_t blb = (size_t)bl * 48;
#define C2_PLANE(kd_, kh_) \
    (x1 + (((blb + (size_t)min(max(d + (kd_) - 1, 0), 47)) * 64 + min(max(h + (kh_) - 1, 0), 63))) * 4096)

    uint4 st[2];
    {
        const u16* src = C2_PLANE(0, 0);
#pragma unroll
        for (int i = 0; i < 2; i++) st[i] = *(const uint4*)(src + (i * 256 + tid) * 8);
    }

#pragma unroll
    for (int kd = 0; kd < 3; kd++) {
#pragma unroll
        for (int kh = 0; kh < 3; kh++) {
            int tap = kd * 3 + kh;

            __syncthreads();                    // (A)
#pragma unroll
            for (int i = 0; i < 2; i++) {
                int idx = i * 256 + tid;        // [0,512)
                *(uint4*)&a_s[(((idx >> 2) + 1) * 5 + (idx & 3)) * 8] = st[i];
            }
            __syncthreads();                    // (B)

            if (tap < 8) {
                int nkd = (tap + 1) / 3, nkh = (tap + 1) % 3;
                const u16* src = C2_PLANE(nkd, nkh);
#pragma unroll
                for (int i = 0; i < 2; i++) st[i] = *(const uint4*)(src + (i * 256 + tid) * 8);
            }

            bool valid = (kd == 0 ? (d > 0) : (kd == 2 ? (d < 47) : true))
                      && (kh == 0 ? (h > 0) : (kh == 2 ? (h < 63) : true));
            if (valid) {
                bf16x8 bfr[2][3];
#pragma unroll
                for (int nt = 0; nt < 2; nt++)
#pragma unroll
                    for (int kc = 0; kc < 3; kc++)
                        bfr[nt][kc] = *(const bf16x8*)(wf + (((size_t)tap * 2 + nt) * 3 + kc) * 512 + lane * 8);

#pragma unroll
                for (int kc = 0; kc < 3; kc++) {
                    int kw = kc;
#pragma unroll
                    for (int mt = 0; mt < 2; mt++) {
                        int wp = (wid * 2 + mt) * 16 + lm + kw;
                        bf16x8 afr = *(const bf16x8*)&a_s[(wp * 5 + q) * 8];
                        acc[mt][0] = __builtin_amdgcn_mfma_f32_16x16x32_bf16(afr, bfr[0][kc], acc[mt][0], 0, 0, 0);
                        acc[mt][1] = __builtin_amdgcn_mfma_f32_16x16x32_bf16(afr, bfr[1][kc], acc[mt][1], 0, 0, 0);
                    }
                }
            }
        }
    }
#undef C2_PLANE

#pragma unroll
    for (int mt = 0; mt < 2; mt++)
#pragma unroll
        for (int nt = 0; nt < 2; nt++) {
            int co = nt * 16 + lm;
            float bs = bias[co];
            float4 o;
            o.x = fmaxf(acc[mt][nt][0] + bs, 0.f);
            o.y = fmaxf(acc[mt][nt][1] + bs, 0.f);
            o.z = fmaxf(acc[mt][nt][2] + bs, 0.f);
            o.w = fmaxf(acc[mt][nt][3] + bs, 0.f);
            int wbase = (wid * 2 + mt) * 16 + q * 4;
            *(float4*)(out + ((((size_t)(b0 + bl) * 32 + co) * 48 + d) * 64 + h) * 128 + wbase) = o;
        }
}

extern "C" void kernel_launch(void* const* d_in, const int* in_sizes, int n_in,
                              void* d_out, int out_size, void* d_ws, size_t ws_size,
                              hipStream_t stream)
{
    const float* lg = (const float*)d_in[0];
    const float* rg = (const float*)d_in[1];
    const float* lc = (const float*)d_in[2];
    const float* rc = (const float*)d_in[3];
    const float* w1 = (const float*)d_in[4];
    const float* g1 = (const float*)d_in[5];
    const float* b1 = (const float*)d_in[6];
    const float* m1 = (const float*)d_in[7];
    const float* v1 = (const float*)d_in[8];
    const float* w2 = (const float*)d_in[9];
    const float* g2 = (const float*)d_in[10];
    const float* b2 = (const float*)d_in[11];
    const float* m2 = (const float*)d_in[12];
    const float* v2 = (const float*)d_in[13];
    (void)in_sizes; (void)n_in; (void)out_size; (void)ws_size;

    // ws layout (total ~50.5 MB << 96 MiB observed ws_size):
    char* ws = (char*)d_ws;
    u16*   wf1   = (u16*)ws;                 // 110,592 B
    u16*   wf2   = (u16*)(ws + 110592);      //  55,296 B
    float* bias1 = (float*)(ws + 165888);    //     128 B
    float* bias2 = (float*)(ws + 166016);    //     128 B
    u16*   x1    = (u16*)(ws + 166144);      // 50,331,648 B  [2][48][64][128][32] bf16

    wfrag_kernel<<<216, 256, 0, stream>>>(w1, g1, b1, m1, v1, wf1, bias1, 64, 6);
    wfrag_kernel<<<108, 256, 0, stream>>>(w2, g2, b2, m2, v2, wf2, bias2, 32, 3);

    // Per batch-pair: vol lives in the d_out region that this pair's conv2
    // output will overwrite (vol is dead by then; regions are byte-identical).
    for (int r = 0; r < 2; r++) {
        u16* vol = (u16*)d_out + (size_t)r * 50331648;   // [2][48][64][128][64] bf16
        vol_build_kernel<<<256, 256, 0, stream>>>(lg, rg, lc, rc, vol, 2 * r);
        conv1_mfma_kernel<<<6144, 256, 0, stream>>>(vol, wf1, bias1, x1);
        conv2_mfma_kernel<<<6144, 256, 0, stream>>>(x1, wf2, bias2, (float*)d_out, 2 * r);
    }
}

// Round 6
// 699.489 us; speedup vs baseline: 1.6616x; 1.6616x over previous
//
#include <hip/hip_runtime.h>
#include <cstdint>
#include <cstddef>

typedef unsigned short u16;
typedef __bf16 bf16x8 __attribute__((ext_vector_type(8)));
typedef float f32x4 __attribute__((ext_vector_type(4)));

#define MAXDISP 48
#define HH 64
#define WW 128

// ---------- bf16 helpers ----------
__device__ __forceinline__ float bf2f(unsigned int x) {
    union { unsigned int i; float f; } c; c.i = x << 16; return c.f;
}
__device__ __forceinline__ float bf2f_hi(unsigned int x) {
    union { unsigned int i; float f; } c; c.i = x & 0xffff0000u; return c.f;
}
__device__ __forceinline__ u16 f2bf(float f) {
    union { float f; unsigned int i; } c; c.f = f;
    unsigned int x = c.i;
    return (u16)((x + 0x7fffu + ((x >> 16) & 1u)) >> 16);   // RNE
}

// ---------- weight transform: BN-fold + swizzle into MFMA B-fragment order ----------
// dst[tap][nt][kc][lane][j] bf16, tap=kd*3+kh, co=nt*16+(lane&15),
// k-chunk kc: CIN=64: kw=kc>>1, c=(kc&1)*32+(lane>>4)*8+j ; CIN=32: kw=kc, c=(lane>>4)*8+j
__global__ __launch_bounds__(256) void wfrag_kernel(
    const float* __restrict__ w, const float* __restrict__ gam,
    const float* __restrict__ bet, const float* __restrict__ mea,
    const float* __restrict__ var,
    u16* __restrict__ dst, float* __restrict__ bias, int CIN, int KC)
{
    int idx = blockIdx.x * 256 + threadIdx.x;
    int n = 9 * 2 * KC * 512;
    if (idx < n) {
        int j    = idx & 7;
        int lane = (idx >> 3) & 63;
        int t2   = idx >> 9;
        int kc   = t2 % KC;
        int t3   = t2 / KC;
        int nt   = t3 & 1;
        int tap  = t3 >> 1;
        int co   = nt * 16 + (lane & 15);
        int qq   = lane >> 4;
        int kw, c;
        if (CIN == 64) { kw = kc >> 1; c = (kc & 1) * 32 + qq * 8 + j; }
        else           { kw = kc;      c = qq * 8 + j; }
        int kd = tap / 3, kh = tap % 3;
        float inv = gam[co] * rsqrtf(var[co] + 1e-5f);
        dst[idx] = f2bf(w[((size_t)co * CIN + c) * 27 + kd * 9 + kh * 3 + kw] * inv);
    }
    if (blockIdx.x == 0 && threadIdx.x < 32) {
        int co = threadIdx.x;
        float inv = gam[co] * rsqrtf(var[co] + 1e-5f);
        bias[co] = bet[co] - mea[co] * inv;
    }
}

// ---------- cost volume, channel-last, PRE-SWIZZLED: vol[bl][d][h][w][c64] bf16 ----------
// Intra-plane layout: 16B-col c16' = c16 ^ ((w+1)&7) so conv1's linear
// global_load_lds staging yields conflict-free swizzled LDS reads (rule #21).
// One launch covers all 4 batches: b = blockIdx>>7, vol region = b>>1.
#define RS 334   // r_s row stride (u16): stride/2 odd -> 2-way-free b32 reads
__global__ __launch_bounds__(256) void vol_build_kernel(
    const float* __restrict__ lg, const float* __restrict__ rg,
    const float* __restrict__ lc, const float* __restrict__ rc,
    u16* __restrict__ vol)
{
    __shared__ u16 r_s[128 * RS];       // [w][0..319 rg | 320..331 rc]
    __shared__ u16 o_s[4 * 128 * 68];   // [dl][w][c64 +4 pad]

    int bi  = blockIdx.x;               // b*128 + dh*64 + h, b in [0,4)
    int h   = bi & 63;
    int dh  = (bi >> 6) & 1;
    int b   = bi >> 7;
    u16* volr = vol + (size_t)(b >> 1) * 50331648;
    int bl  = b & 1;
    int tid = threadIdx.x;
    int w    = tid & 127;
    int part = tid >> 7;

    for (int idx = tid; idx < 320 * 32; idx += 256) {
        int c = idx >> 5, w4 = (idx & 31) << 2;
        const float4 v = *(const float4*)(rg + (((size_t)b * 320 + c) * 64 + h) * 128 + w4);
        r_s[(w4 + 0) * RS + c] = f2bf(v.x);
        r_s[(w4 + 1) * RS + c] = f2bf(v.y);
        r_s[(w4 + 2) * RS + c] = f2bf(v.z);
        r_s[(w4 + 3) * RS + c] = f2bf(v.w);
    }
    for (int idx = tid; idx < 12 * 32; idx += 256) {
        int c = idx >> 5, w4 = (idx & 31) << 2;
        const float4 v = *(const float4*)(rc + (((size_t)b * 12 + c) * 64 + h) * 128 + w4);
        r_s[(w4 + 0) * RS + 320 + c] = f2bf(v.x);
        r_s[(w4 + 1) * RS + 320 + c] = f2bf(v.y);
        r_s[(w4 + 2) * RS + 320 + c] = f2bf(v.z);
        r_s[(w4 + 3) * RS + 320 + c] = f2bf(v.w);
    }
    u16 lcv[12];
    if (part == 0) {
#pragma unroll
        for (int k = 0; k < 12; k++)
            lcv[k] = f2bf(lc[(((size_t)b * 12 + k) * 64 + h) * 128 + w]);
    }
    __syncthreads();

    int d0 = dh * 24;
    for (int dc = 0; dc < 24; dc += 4) {
        // ---- corr channels: part0 g 0..19, part1 g 20..39 ----
        for (int gb = 0; gb < 5; gb++) {
            int g0 = part * 20 + gb * 4;
            float lv[4][8];
#pragma unroll
            for (int gg = 0; gg < 4; gg++)
#pragma unroll
                for (int j = 0; j < 8; j++)
                    lv[gg][j] = lg[(((size_t)b * 320 + (g0 + gg) * 8 + j) * 64 + h) * 128 + w];
#pragma unroll
            for (int dl = 0; dl < 4; dl++) {
                int d = d0 + dc + dl;
                union { u16 us[4]; uint2 u2; } pk;
                pk.us[0] = pk.us[1] = pk.us[2] = pk.us[3] = 0;
                if (w >= d) {
#pragma unroll
                    for (int gg = 0; gg < 4; gg++) {
                        float s = 0.f;
                        int base = (w - d) * RS + (g0 + gg) * 8;
#pragma unroll
                        for (int jj = 0; jj < 4; jj++) {
                            unsigned int uu = *(const unsigned int*)&r_s[base + jj * 2];
                            s += lv[gg][jj * 2]     * bf2f(uu & 0xffffu);
                            s += lv[gg][jj * 2 + 1] * bf2f_hi(uu);
                        }
                        pk.us[gg] = f2bf(s * 0.125f);
                    }
                }
                *(uint2*)&o_s[(dl * 128 + w) * 68 + g0] = pk.u2;
            }
        }
        // ---- concat channels ----
#pragma unroll
        for (int dl = 0; dl < 4; dl++) {
            int d = d0 + dc + dl;
            union { u16 us[12]; uint2 u2[3]; } z;
            if (part == 0) {
#pragma unroll
                for (int k = 0; k < 12; k++) z.us[k] = (w >= d) ? lcv[k] : (u16)0;
                u16* dst = &o_s[(dl * 128 + w) * 68 + 40];
                *(uint2*)(dst + 0) = z.u2[0];
                *(uint2*)(dst + 4) = z.u2[1];
                *(uint2*)(dst + 8) = z.u2[2];
            } else {
                if (w >= d) {
                    int base = (w - d) * RS + 320;
#pragma unroll
                    for (int k = 0; k < 12; k++) z.us[k] = r_s[base + k];
                } else {
#pragma unroll
                    for (int k = 0; k < 12; k++) z.us[k] = 0;
                }
                u16* dst = &o_s[(dl * 128 + w) * 68 + 52];
                *(uint2*)(dst + 0) = z.u2[0];
                *(uint2*)(dst + 4) = z.u2[1];
                *(uint2*)(dst + 8) = z.u2[2];
            }
        }
        __syncthreads();
        // ---- flush 4 d-slabs, coalesced, col-swizzled c16^=(w+1)&7 ----
#pragma unroll
        for (int i = 0; i < 16; i++) {
            int idx = i * 256 + tid;            // [0,4096)
            int dl  = idx >> 10;
            int rem = idx & 1023;
            int ww  = rem >> 3, cg = rem & 7;
            const u16* sp = &o_s[(dl * 128 + ww) * 68 + cg * 8];
            uint2 lo = *(const uint2*)sp;
            uint2 hi = *(const uint2*)(sp + 4);
            uint4 ov = { lo.x, lo.y, hi.x, hi.y };
            int d = d0 + dc + dl;
            *(uint4*)(volr + ((((size_t)bl * 48 + d) * 64 + h) * 128 + ww) * 64
                             + ((cg ^ ((ww + 1) & 7)) << 3)) = ov;
        }
        __syncthreads();
    }
}

// ---------- conv1: implicit-GEMM MFMA, global_load_lds double-buffered 2-phase ----------
// Per tap: issue next tap's DMA (no VGPRs involved) -> weights + ds_read + 24 MFMA
// from current buffer -> one __syncthreads (vmcnt drain lands after MFMA cover).
// LDS rows linear 128B (DMA requirement); cols pre-swizzled by vol_build -> 2-way-free reads.
__global__ __launch_bounds__(256) void conv1_mfma_kernel(
    const u16* __restrict__ vol, const u16* __restrict__ wf,
    const float* __restrict__ bias, u16* __restrict__ x1)
{
    __shared__ u16 a_s[2][130 * 64];   // [wp][c16'*8], wp=w+1, rows 0/129 = zero halo

    int p  = blockIdx.x;
    int bi = (p & 7) * 768 + (p >> 3);   // 6144 = 8 XCDs * 768: contiguous chunk per XCD
    int h  = bi & 63;
    int t1 = bi >> 6;
    int d  = t1 % 48;
    int bl = t1 / 48;
    int tid  = threadIdx.x;
    int lane = tid & 63, wid = tid >> 6;
    int lm = lane & 15, q = lane >> 4;

    // zero halo rows (wp=0,129) in both buffers; DMA writes rows 1..128 only
    if (tid < 32) {
        uint4 z = { 0, 0, 0, 0 };
        int bb = tid >> 4, t = tid & 15;
        int wp = (t >> 3) ? 129 : 0;
        *(uint4*)&a_s[bb][wp * 64 + (t & 7) * 8] = z;
    }

    f32x4 acc[2][2];
#pragma unroll
    for (int i = 0; i < 2; i++)
#pragma unroll
        for (int j = 0; j < 2; j++) acc[i][j] = { 0.f, 0.f, 0.f, 0.f };

    const size_t blb = (size_t)bl * 48;

    auto stage = [&](int bb, int kd_, int kh_) {
        int dd = d + kd_ - 1; dd = dd < 0 ? 0 : (dd > 47 ? 47 : dd);
        int hh = h + kh_ - 1; hh = hh < 0 ? 0 : (hh > 63 ? 63 : hh);
        const u16* src = vol + ((blb + (size_t)dd) * 64 + hh) * 8192;
        u16* dst = &a_s[bb][64];                       // row 1
#pragma unroll
        for (int i = 0; i < 4; i++) {
            __builtin_amdgcn_global_load_lds(
                (const __attribute__((address_space(1))) unsigned int*)(const void*)(src + (i * 256 + tid) * 8),
                (__attribute__((address_space(3))) unsigned int*)(void*)(dst + (i * 256 + tid) * 8),
                16, 0, 0);
        }
    };

    stage(0, 0, 0);
    __syncthreads();                                   // drain prologue DMA + halo writes

#pragma unroll
    for (int kd = 0; kd < 3; kd++) {
#pragma unroll
        for (int kh = 0; kh < 3; kh++) {
            const int tap = kd * 3 + kh;
            if (tap < 8) stage((tap + 1) & 1, (tap + 1) / 3, (tap + 1) % 3);

            bool valid = (kd == 0 ? (d > 0) : (kd == 2 ? (d < 47) : true))
                      && (kh == 0 ? (h > 0) : (kh == 2 ? (h < 63) : true));
            if (valid) {
                const u16* as = a_s[tap & 1];
                bf16x8 bfr[2][6];
#pragma unroll
                for (int nt = 0; nt < 2; nt++)
#pragma unroll
                    for (int kc = 0; kc < 6; kc++)
                        bfr[nt][kc] = *(const bf16x8*)(wf + (((size_t)tap * 2 + nt) * 6 + kc) * 512 + lane * 8);

#pragma unroll
                for (int kc = 0; kc < 6; kc++) {
                    int kw = kc >> 1;
                    int cg = (kc & 1) * 4 + q;
#pragma unroll
                    for (int mt = 0; mt < 2; mt++) {
                        int wp = (wid * 2 + mt) * 16 + lm + kw;
                        bf16x8 afr = *(const bf16x8*)&as[wp * 64 + ((cg ^ (wp & 7)) << 3)];
                        acc[mt][0] = __builtin_amdgcn_mfma_f32_16x16x32_bf16(afr, bfr[0][kc], acc[mt][0], 0, 0, 0);
                        acc[mt][1] = __builtin_amdgcn_mfma_f32_16x16x32_bf16(afr, bfr[1][kc], acc[mt][1], 0, 0, 0);
                    }
                }
            }
            __syncthreads();                           // drain next tap's DMA (covered by MFMA)
        }
    }

    // epilogue -> x1, paired-row swizzled layout for conv2's linear DMA staging:
    // plane u16 idx = (wp>>1)*64 + ((wp&1)*4 + ((co>>3)^((wp>>1)&3)))*8 + (co&7) - 32, wp=w+1
    u16* xb = x1 + ((blb + d) * 64 + h) * 4096;
#pragma unroll
    for (int mt = 0; mt < 2; mt++)
#pragma unroll
        for (int nt = 0; nt < 2; nt++) {
            int co = nt * 16 + lm;
            float bs = bias[co];
#pragma unroll
            for (int r = 0; r < 4; r++) {
                int w = (wid * 2 + mt) * 16 + q * 4 + r;
                int wp = w + 1, wq = wp >> 1, odd = wp & 1;
                int c16s = (co >> 3) ^ (wq & 3);
                xb[wq * 64 + (odd * 4 + c16s) * 8 + (co & 7) - 32] =
                    f2bf(fmaxf(acc[mt][nt][r] + bs, 0.f));
            }
        }
}

// ---------- conv2: same 2-phase DMA structure, CIN=32, paired-row LDS (128B rows) ----------
__global__ __launch_bounds__(256) void conv2_mfma_kernel(
    const u16* __restrict__ x1, const u16* __restrict__ wf,
    const float* __restrict__ bias, float* __restrict__ out, int b0)
{
    __shared__ u16 a_s[2][65 * 64];   // LDS row = wp>>1 (128B), col'=(wp&1)*4 + (c16^((wp>>1)&3))

    int p  = blockIdx.x;
    int bi = (p & 7) * 768 + (p >> 3);
    int h  = bi & 63;
    int t1 = bi >> 6;
    int d  = t1 % 48;
    int bl = t1 / 48;
    int tid  = threadIdx.x;
    int lane = tid & 63, wid = tid >> 6;
    int lm = lane & 15, q = lane >> 4;

    // halo: u16 [0,32) = wp0 (w=-1), [4128,4160) = wp129 (w=128), both buffers
    if (tid < 16) {
        uint4 z = { 0, 0, 0, 0 };
        int bb = tid >> 3, t = tid & 7;
        int base = (t >> 2) ? 4128 : 0;
        *(uint4*)&a_s[bb][base + (t & 3) * 8] = z;
    }

    f32x4 acc[2][2];
#pragma unroll
    for (int i = 0; i < 2; i++)
#pragma unroll
        for (int j = 0; j < 2; j++) acc[i][j] = { 0.f, 0.f, 0.f, 0.f };

    const size_t blb = (size_t)bl * 48;

    auto stage = [&](int bb, int kd_, int kh_) {
        int dd = d + kd_ - 1; dd = dd < 0 ? 0 : (dd > 47 ? 47 : dd);
        int hh = h + kh_ - 1; hh = hh < 0 ? 0 : (hh > 63 ? 63 : hh);
        const u16* src = x1 + ((blb + (size_t)dd) * 64 + hh) * 4096;
        u16* dst = &a_s[bb][32];                       // after w=-1 halo half-row
#pragma unroll
        for (int i = 0; i < 2; i++) {
            __builtin_amdgcn_global_load_lds(
                (const __attribute__((address_space(1))) unsigned int*)(const void*)(src + (i * 256 + tid) * 8),
                (__attribute__((address_space(3))) unsigned int*)(void*)(dst + (i * 256 + tid) * 8),
                16, 0, 0);
        }
    };

    stage(0, 0, 0);
    __syncthreads();

#pragma unroll
    for (int kd = 0; kd < 3; kd++) {
#pragma unroll
        for (int kh = 0; kh < 3; kh++) {
            const int tap = kd * 3 + kh;
            if (tap < 8) stage((tap + 1) & 1, (tap + 1) / 3, (tap + 1) % 3);

            bool valid = (kd == 0 ? (d > 0) : (kd == 2 ? (d < 47) : true))
                      && (kh == 0 ? (h > 0) : (kh == 2 ? (h < 63) : true));
            if (valid) {
                const u16* as = a_s[tap & 1];
                bf16x8 bfr[2][3];
#pragma unroll
                for (int nt = 0; nt < 2; nt++)
#pragma unroll
                    for (int kc = 0; kc < 3; kc++)
                        bfr[nt][kc] = *(const bf16x8*)(wf + (((size_t)tap * 2 + nt) * 3 + kc) * 512 + lane * 8);

#pragma unroll
                for (int kc = 0; kc < 3; kc++) {
                    int kw = kc;
#pragma unroll
                    for (int mt = 0; mt < 2; mt++) {
                        int wp = (wid * 2 + mt) * 16 + lm + kw;
                        int wq = wp >> 1;
                        bf16x8 afr = *(const bf16x8*)&as[wq * 64 + (((wp & 1) * 4 + (q ^ (wq & 3))) << 3)];
                        acc[mt][0] = __builtin_amdgcn_mfma_f32_16x16x32_bf16(afr, bfr[0][kc], acc[mt][0], 0, 0, 0);
                        acc[mt][1] = __builtin_amdgcn_mfma_f32_16x16x32_bf16(afr, bfr[1][kc], acc[mt][1], 0, 0, 0);
                    }
                }
            }
            __syncthreads();
        }
    }

#pragma unroll
    for (int mt = 0; mt < 2; mt++)
#pragma unroll
        for (int nt = 0; nt < 2; nt++) {
            int co = nt * 16 + lm;
            float bs = bias[co];
            float4 o;
            o.x = fmaxf(acc[mt][nt][0] + bs, 0.f);
            o.y = fmaxf(acc[mt][nt][1] + bs, 0.f);
            o.z = fmaxf(acc[mt][nt][2] + bs, 0.f);
            o.w = fmaxf(acc[mt][nt][3] + bs, 0.f);
            int wbase = (wid * 2 + mt) * 16 + q * 4;
            *(float4*)(out + ((((size_t)(b0 + bl) * 32 + co) * 48 + d) * 64 + h) * 128 + wbase) = o;
        }
}

extern "C" void kernel_launch(void* const* d_in, const int* in_sizes, int n_in,
                              void* d_out, int out_size, void* d_ws, size_t ws_size,
                              hipStream_t stream)
{
    const float* lg = (const float*)d_in[0];
    const float* rg = (const float*)d_in[1];
    const float* lc = (const float*)d_in[2];
    const float* rc = (const float*)d_in[3];
    const float* w1 = (const float*)d_in[4];
    const float* g1 = (const float*)d_in[5];
    const float* b1 = (const float*)d_in[6];
    const float* m1 = (const float*)d_in[7];
    const float* v1 = (const float*)d_in[8];
    const float* w2 = (const float*)d_in[9];
    const float* g2 = (const float*)d_in[10];
    const float* b2 = (const float*)d_in[11];
    const float* m2 = (const float*)d_in[12];
    const float* v2 = (const float*)d_in[13];
    (void)in_sizes; (void)n_in; (void)out_size; (void)ws_size;

    // ws layout (total ~50.5 MB << 96 MiB observed ws_size):
    char* ws = (char*)d_ws;
    u16*   wf1   = (u16*)ws;                 // 110,592 B
    u16*   wf2   = (u16*)(ws + 110592);      //  55,296 B
    float* bias1 = (float*)(ws + 165888);    //     128 B
    float* bias2 = (float*)(ws + 166016);    //     128 B
    u16*   x1    = (u16*)(ws + 166144);      // 50,331,648 B  [2][48][64][128][32] bf16

    wfrag_kernel<<<216, 256, 0, stream>>>(w1, g1, b1, m1, v1, wf1, bias1, 64, 6);
    wfrag_kernel<<<108, 256, 0, stream>>>(w2, g2, b2, m2, v2, wf2, bias2, 32, 3);

    // Both vol regions built in one launch (d_out byte-identical regions; vol r is
    // dead before conv2 r overwrites it). Then per pair: conv1 -> x1 -> conv2.
    vol_build_kernel<<<512, 256, 0, stream>>>(lg, rg, lc, rc, (u16*)d_out);
    for (int r = 0; r < 2; r++) {
        u16* vol = (u16*)d_out + (size_t)r * 50331648;   // [2][48][64][128][64] bf16
        conv1_mfma_kernel<<<6144, 256, 0, stream>>>(vol, wf1, bias1, x1);
        conv2_mfma_kernel<<<6144, 256, 0, stream>>>(x1, wf2, bias2, (float*)d_out, 2 * r);
    }
}

// Round 7
// 656.670 us; speedup vs baseline: 1.7699x; 1.0652x over previous
//
#include <hip/hip_runtime.h>
#include <cstdint>
#include <cstddef>

typedef unsigned short u16;
typedef __bf16 bf16x8 __attribute__((ext_vector_type(8)));
typedef float f32x4 __attribute__((ext_vector_type(4)));

#define MAXDISP 48
#define HH 64
#define WW 128

// ---------- bf16 helpers ----------
__device__ __forceinline__ float bf2f(unsigned int x) {
    union { unsigned int i; float f; } c; c.i = x << 16; return c.f;
}
__device__ __forceinline__ float bf2f_hi(unsigned int x) {
    union { unsigned int i; float f; } c; c.i = x & 0xffff0000u; return c.f;
}
__device__ __forceinline__ u16 f2bf(float f) {
    union { float f; unsigned int i; } c; c.f = f;
    unsigned int x = c.i;
    return (u16)((x + 0x7fffu + ((x >> 16) & 1u)) >> 16);   // RNE
}

// ---------- weight transform: BN-fold + swizzle into MFMA B-fragment order ----------
// dst[tap][nt][kc][lane][j] bf16, tap=kd*3+kh, co=nt*16+(lane&15),
// k-chunk kc: CIN=64: kw=kc>>1, c=(kc&1)*32+(lane>>4)*8+j ; CIN=32: kw=kc, c=(lane>>4)*8+j
__global__ __launch_bounds__(256) void wfrag_kernel(
    const float* __restrict__ w, const float* __restrict__ gam,
    const float* __restrict__ bet, const float* __restrict__ mea,
    const float* __restrict__ var,
    u16* __restrict__ dst, float* __restrict__ bias, int CIN, int KC)
{
    int idx = blockIdx.x * 256 + threadIdx.x;
    int n = 9 * 2 * KC * 512;
    if (idx < n) {
        int j    = idx & 7;
        int lane = (idx >> 3) & 63;
        int t2   = idx >> 9;
        int kc   = t2 % KC;
        int t3   = t2 / KC;
        int nt   = t3 & 1;
        int tap  = t3 >> 1;
        int co   = nt * 16 + (lane & 15);
        int qq   = lane >> 4;
        int kw, c;
        if (CIN == 64) { kw = kc >> 1; c = (kc & 1) * 32 + qq * 8 + j; }
        else           { kw = kc;      c = qq * 8 + j; }
        int kd = tap / 3, kh = tap % 3;
        float inv = gam[co] * rsqrtf(var[co] + 1e-5f);
        dst[idx] = f2bf(w[((size_t)co * CIN + c) * 27 + kd * 9 + kh * 3 + kw] * inv);
    }
    if (blockIdx.x == 0 && threadIdx.x < 32) {
        int co = threadIdx.x;
        float inv = gam[co] * rsqrtf(var[co] + 1e-5f);
        bias[co] = bet[co] - mea[co] * inv;
    }
}

// ---------- cost volume, channel-last, PRE-SWIZZLED: vol[bl][d][h][w][c64] bf16 ----------
// Intra-plane layout: 16B-col c16' = c16 ^ ((w+1)&7) so conv1's linear
// global_load_lds staging yields conflict-free swizzled LDS reads (rule #21).
// 512 threads/block (8 waves): LDS caps at 1 block/CU, so widen the block for TLP.
#define RS 334   // r_s row stride (u16): stride/2 odd -> 2-way-free b32 reads
__global__ __launch_bounds__(512) void vol_build_kernel(
    const float* __restrict__ lg, const float* __restrict__ rg,
    const float* __restrict__ lc, const float* __restrict__ rc,
    u16* __restrict__ vol)
{
    __shared__ u16 r_s[128 * RS];       // [w][0..319 rg | 320..331 rc]
    __shared__ u16 o_s[4 * 128 * 68];   // [dl][w][c64 +4 pad]

    int bi  = blockIdx.x;               // b*128 + dh*64 + h, b in [0,4)
    int h   = bi & 63;
    int dh  = (bi >> 6) & 1;
    int b   = bi >> 7;
    u16* volr = vol + (size_t)(b >> 1) * 50331648;
    int bl  = b & 1;
    int tid = threadIdx.x;
    int w    = tid & 127;
    int part = tid >> 7;                // [0,4)

    for (int idx = tid; idx < 320 * 32; idx += 512) {
        int c = idx >> 5, w4 = (idx & 31) << 2;
        const float4 v = *(const float4*)(rg + (((size_t)b * 320 + c) * 64 + h) * 128 + w4);
        r_s[(w4 + 0) * RS + c] = f2bf(v.x);
        r_s[(w4 + 1) * RS + c] = f2bf(v.y);
        r_s[(w4 + 2) * RS + c] = f2bf(v.z);
        r_s[(w4 + 3) * RS + c] = f2bf(v.w);
    }
    for (int idx = tid; idx < 12 * 32; idx += 512) {
        int c = idx >> 5, w4 = (idx & 31) << 2;
        const float4 v = *(const float4*)(rc + (((size_t)b * 12 + c) * 64 + h) * 128 + w4);
        r_s[(w4 + 0) * RS + 320 + c] = f2bf(v.x);
        r_s[(w4 + 1) * RS + 320 + c] = f2bf(v.y);
        r_s[(w4 + 2) * RS + 320 + c] = f2bf(v.z);
        r_s[(w4 + 3) * RS + 320 + c] = f2bf(v.w);
    }
    u16 lcv[12];
    if (part == 0) {
#pragma unroll
        for (int k = 0; k < 12; k++)
            lcv[k] = f2bf(lc[(((size_t)b * 12 + k) * 64 + h) * 128 + w]);
    }
    __syncthreads();

    int d0 = dh * 24;
    for (int dc = 0; dc < 24; dc += 4) {
        // ---- corr channels: part p owns groups [p*10, p*10+10), 2 at a time ----
        for (int gb = 0; gb < 5; gb++) {
            int g0 = part * 10 + gb * 2;
            float lv[2][8];
#pragma unroll
            for (int gg = 0; gg < 2; gg++)
#pragma unroll
                for (int j = 0; j < 8; j++)
                    lv[gg][j] = lg[(((size_t)b * 320 + (g0 + gg) * 8 + j) * 64 + h) * 128 + w];
#pragma unroll
            for (int dl = 0; dl < 4; dl++) {
                int d = d0 + dc + dl;
                union { u16 us[2]; unsigned int u1; } pk;
                pk.us[0] = pk.us[1] = 0;
                if (w >= d) {
#pragma unroll
                    for (int gg = 0; gg < 2; gg++) {
                        float s = 0.f;
                        int base = (w - d) * RS + (g0 + gg) * 8;
#pragma unroll
                        for (int jj = 0; jj < 4; jj++) {
                            unsigned int uu = *(const unsigned int*)&r_s[base + jj * 2];
                            s += lv[gg][jj * 2]     * bf2f(uu & 0xffffu);
                            s += lv[gg][jj * 2 + 1] * bf2f_hi(uu);
                        }
                        pk.us[gg] = f2bf(s * 0.125f);
                    }
                }
                *(unsigned int*)&o_s[(dl * 128 + w) * 68 + g0] = pk.u1;
            }
        }
        // ---- concat channels (parts 0,1 only) ----
#pragma unroll
        for (int dl = 0; dl < 4; dl++) {
            int d = d0 + dc + dl;
            union { u16 us[12]; uint2 u2[3]; } z;
            if (part == 0) {
#pragma unroll
                for (int k = 0; k < 12; k++) z.us[k] = (w >= d) ? lcv[k] : (u16)0;
                u16* dst = &o_s[(dl * 128 + w) * 68 + 40];
                *(uint2*)(dst + 0) = z.u2[0];
                *(uint2*)(dst + 4) = z.u2[1];
                *(uint2*)(dst + 8) = z.u2[2];
            } else if (part == 1) {
                if (w >= d) {
                    int base = (w - d) * RS + 320;
#pragma unroll
                    for (int k = 0; k < 12; k++) z.us[k] = r_s[base + k];
                } else {
#pragma unroll
                    for (int k = 0; k < 12; k++) z.us[k] = 0;
                }
                u16* dst = &o_s[(dl * 128 + w) * 68 + 52];
                *(uint2*)(dst + 0) = z.u2[0];
                *(uint2*)(dst + 4) = z.u2[1];
                *(uint2*)(dst + 8) = z.u2[2];
            }
        }
        __syncthreads();
        // ---- flush 4 d-slabs, coalesced, col-swizzled c16^=(w+1)&7 ----
#pragma unroll
        for (int i = 0; i < 8; i++) {
            int idx = i * 512 + tid;            // [0,4096)
            int dl  = idx >> 10;
            int rem = idx & 1023;
            int ww  = rem >> 3, cg = rem & 7;
            const u16* sp = &o_s[(dl * 128 + ww) * 68 + cg * 8];
            uint2 lo = *(const uint2*)sp;
            uint2 hi = *(const uint2*)(sp + 4);
            uint4 ov = { lo.x, lo.y, hi.x, hi.y };
            int d = d0 + dc + dl;
            *(uint4*)(volr + ((((size_t)bl * 48 + d) * 64 + h) * 128 + ww) * 64
                             + ((cg ^ ((ww + 1) & 7)) << 3)) = ov;
        }
        __syncthreads();
    }
}

// ---------- conv1: implicit-GEMM MFMA, global_load_lds 2-phase, vmcnt-ordered ----------
// Per tap: weight loads issued FIRST (oldest VMEM), then next tap's 4 DMA ops
// (newest). The s_waitcnt before the MFMA cluster can then be vmcnt(4) — the DMA
// stays in flight across the compute phase and is drained only at the barrier.
// sched_barrier(0) pins the issue order against the machine scheduler.
__global__ __launch_bounds__(256) void conv1_mfma_kernel(
    const u16* __restrict__ vol, const u16* __restrict__ wf,
    const float* __restrict__ bias, u16* __restrict__ x1)
{
    __shared__ u16 a_s[2][130 * 64];   // [wp][c16'*8], wp=w+1, rows 0/129 = zero halo

    int p  = blockIdx.x;
    int bi = (p & 7) * 768 + (p >> 3);   // 6144 = 8 XCDs * 768: contiguous chunk per XCD
    int h  = bi & 63;
    int t1 = bi >> 6;
    int d  = t1 % 48;
    int bl = t1 / 48;
    int tid  = threadIdx.x;
    int lane = tid & 63, wid = tid >> 6;
    int lm = lane & 15, q = lane >> 4;

    // zero halo rows (wp=0,129) in both buffers; DMA writes rows 1..128 only
    if (tid < 32) {
        uint4 z = { 0, 0, 0, 0 };
        int bb = tid >> 4, t = tid & 15;
        int wp = (t >> 3) ? 129 : 0;
        *(uint4*)&a_s[bb][wp * 64 + (t & 7) * 8] = z;
    }

    f32x4 acc[2][2];
#pragma unroll
    for (int i = 0; i < 2; i++)
#pragma unroll
        for (int j = 0; j < 2; j++) acc[i][j] = { 0.f, 0.f, 0.f, 0.f };

    const size_t blb = (size_t)bl * 48;

    auto stage = [&](int bb, int kd_, int kh_) {
        int dd = d + kd_ - 1; dd = dd < 0 ? 0 : (dd > 47 ? 47 : dd);
        int hh = h + kh_ - 1; hh = hh < 0 ? 0 : (hh > 63 ? 63 : hh);
        const u16* src = vol + ((blb + (size_t)dd) * 64 + hh) * 8192;
        u16* dst = &a_s[bb][64];                       // row 1
#pragma unroll
        for (int i = 0; i < 4; i++) {
            __builtin_amdgcn_global_load_lds(
                (const __attribute__((address_space(1))) unsigned int*)(const void*)(src + (i * 256 + tid) * 8),
                (__attribute__((address_space(3))) unsigned int*)(void*)(dst + (i * 256 + tid) * 8),
                16, 0, 0);
        }
    };

    stage(0, 0, 0);
    __syncthreads();                                   // drain prologue DMA + halo writes

#pragma unroll
    for (int kd = 0; kd < 3; kd++) {
#pragma unroll
        for (int kh = 0; kh < 3; kh++) {
            const int tap = kd * 3 + kh;
            bool valid = (kd == 0 ? (d > 0) : (kd == 2 ? (d < 47) : true))
                      && (kh == 0 ? (h > 0) : (kh == 2 ? (h < 63) : true));

            bf16x8 bfr[2][6];
            if (valid) {                               // weights = OLDEST outstanding VMEM
#pragma unroll
                for (int nt = 0; nt < 2; nt++)
#pragma unroll
                    for (int kc = 0; kc < 6; kc++)
                        bfr[nt][kc] = *(const bf16x8*)(wf + (((size_t)tap * 2 + nt) * 6 + kc) * 512 + lane * 8);
            }
            __builtin_amdgcn_sched_barrier(0);         // pin: weights before DMA
            if (tap < 8) stage((tap + 1) & 1, (tap + 1) / 3, (tap + 1) % 3);

            if (valid) {
                const u16* as = a_s[tap & 1];
#pragma unroll
                for (int kc = 0; kc < 6; kc++) {
                    int kw = kc >> 1;
                    int cg = (kc & 1) * 4 + q;
#pragma unroll
                    for (int mt = 0; mt < 2; mt++) {
                        int wp = (wid * 2 + mt) * 16 + lm + kw;
                        bf16x8 afr = *(const bf16x8*)&as[wp * 64 + ((cg ^ (wp & 7)) << 3)];
                        acc[mt][0] = __builtin_amdgcn_mfma_f32_16x16x32_bf16(afr, bfr[0][kc], acc[mt][0], 0, 0, 0);
                        acc[mt][1] = __builtin_amdgcn_mfma_f32_16x16x32_bf16(afr, bfr[1][kc], acc[mt][1], 0, 0, 0);
                    }
                }
            }
            __syncthreads();                           // drain next tap's DMA (covered by MFMA)
        }
    }

    // epilogue -> x1, paired-row swizzled layout for conv2's linear DMA staging:
    // plane u16 idx = (wp>>1)*64 + ((wp&1)*4 + ((co>>3)^((wp>>1)&3)))*8 + (co&7) - 32, wp=w+1
    u16* xb = x1 + ((blb + d) * 64 + h) * 4096;
#pragma unroll
    for (int mt = 0; mt < 2; mt++)
#pragma unroll
        for (int nt = 0; nt < 2; nt++) {
            int co = nt * 16 + lm;
            float bs = bias[co];
#pragma unroll
            for (int r = 0; r < 4; r++) {
                int w = (wid * 2 + mt) * 16 + q * 4 + r;
                int wp = w + 1, wq = wp >> 1, odd = wp & 1;
                int c16s = (co >> 3) ^ (wq & 3);
                xb[wq * 64 + (odd * 4 + c16s) * 8 + (co & 7) - 32] =
                    f2bf(fmaxf(acc[mt][nt][r] + bs, 0.f));
            }
        }
}

// ---------- conv2: same 2-phase DMA structure, CIN=32, paired-row LDS (128B rows) ----------
__global__ __launch_bounds__(256) void conv2_mfma_kernel(
    const u16* __restrict__ x1, const u16* __restrict__ wf,
    const float* __restrict__ bias, float* __restrict__ out, int b0)
{
    __shared__ u16 a_s[2][65 * 64];   // LDS row = wp>>1 (128B), col'=(wp&1)*4 + (c16^((wp>>1)&3))

    int p  = blockIdx.x;
    int bi = (p & 7) * 768 + (p >> 3);
    int h  = bi & 63;
    int t1 = bi >> 6;
    int d  = t1 % 48;
    int bl = t1 / 48;
    int tid  = threadIdx.x;
    int lane = tid & 63, wid = tid >> 6;
    int lm = lane & 15, q = lane >> 4;

    // halo: u16 [0,32) = wp0 (w=-1), [4128,4160) = wp129 (w=128), both buffers
    if (tid < 16) {
        uint4 z = { 0, 0, 0, 0 };
        int bb = tid >> 3, t = tid & 7;
        int base = (t >> 2) ? 4128 : 0;
        *(uint4*)&a_s[bb][base + (t & 3) * 8] = z;
    }

    f32x4 acc[2][2];
#pragma unroll
    for (int i = 0; i < 2; i++)
#pragma unroll
        for (int j = 0; j < 2; j++) acc[i][j] = { 0.f, 0.f, 0.f, 0.f };

    const size_t blb = (size_t)bl * 48;

    auto stage = [&](int bb, int kd_, int kh_) {
        int dd = d + kd_ - 1; dd = dd < 0 ? 0 : (dd > 47 ? 47 : dd);
        int hh = h + kh_ - 1; hh = hh < 0 ? 0 : (hh > 63 ? 63 : hh);
        const u16* src = x1 + ((blb + (size_t)dd) * 64 + hh) * 4096;
        u16* dst = &a_s[bb][32];                       // after w=-1 halo half-row
#pragma unroll
        for (int i = 0; i < 2; i++) {
            __builtin_amdgcn_global_load_lds(
                (const __attribute__((address_space(1))) unsigned int*)(const void*)(src + (i * 256 + tid) * 8),
                (__attribute__((address_space(3))) unsigned int*)(void*)(dst + (i * 256 + tid) * 8),
                16, 0, 0);
        }
    };

    stage(0, 0, 0);
    __syncthreads();

#pragma unroll
    for (int kd = 0; kd < 3; kd++) {
#pragma unroll
        for (int kh = 0; kh < 3; kh++) {
            const int tap = kd * 3 + kh;
            bool valid = (kd == 0 ? (d > 0) : (kd == 2 ? (d < 47) : true))
                      && (kh == 0 ? (h > 0) : (kh == 2 ? (h < 63) : true));

            bf16x8 bfr[2][3];
            if (valid) {                               // weights first (oldest VMEM)
#pragma unroll
                for (int nt = 0; nt < 2; nt++)
#pragma unroll
                    for (int kc = 0; kc < 3; kc++)
                        bfr[nt][kc] = *(const bf16x8*)(wf + (((size_t)tap * 2 + nt) * 3 + kc) * 512 + lane * 8);
            }
            __builtin_amdgcn_sched_barrier(0);
            if (tap < 8) stage((tap + 1) & 1, (tap + 1) / 3, (tap + 1) % 3);

            if (valid) {
                const u16* as = a_s[tap & 1];
#pragma unroll
                for (int kc = 0; kc < 3; kc++) {
                    int kw = kc;
#pragma unroll
                    for (int mt = 0; mt < 2; mt++) {
                        int wp = (wid * 2 + mt) * 16 + lm + kw;
                        int wq = wp >> 1;
                        bf16x8 afr = *(const bf16x8*)&as[wq * 64 + (((wp & 1) * 4 + (q ^ (wq & 3))) << 3)];
                        acc[mt][0] = __builtin_amdgcn_mfma_f32_16x16x32_bf16(afr, bfr[0][kc], acc[mt][0], 0, 0, 0);
                        acc[mt][1] = __builtin_amdgcn_mfma_f32_16x16x32_bf16(afr, bfr[1][kc], acc[mt][1], 0, 0, 0);
                    }
                }
            }
            __syncthreads();
        }
    }

#pragma unroll
    for (int mt = 0; mt < 2; mt++)
#pragma unroll
        for (int nt = 0; nt < 2; nt++) {
            int co = nt * 16 + lm;
            float bs = bias[co];
            float4 o;
            o.x = fmaxf(acc[mt][nt][0] + bs, 0.f);
            o.y = fmaxf(acc[mt][nt][1] + bs, 0.f);
            o.z = fmaxf(acc[mt][nt][2] + bs, 0.f);
            o.w = fmaxf(acc[mt][nt][3] + bs, 0.f);
            int wbase = (wid * 2 + mt) * 16 + q * 4;
            *(float4*)(out + ((((size_t)(b0 + bl) * 32 + co) * 48 + d) * 64 + h) * 128 + wbase) = o;
        }
}

extern "C" void kernel_launch(void* const* d_in, const int* in_sizes, int n_in,
                              void* d_out, int out_size, void* d_ws, size_t ws_size,
                              hipStream_t stream)
{
    const float* lg = (const float*)d_in[0];
    const float* rg = (const float*)d_in[1];
    const float* lc = (const float*)d_in[2];
    const float* rc = (const float*)d_in[3];
    const float* w1 = (const float*)d_in[4];
    const float* g1 = (const float*)d_in[5];
    const float* b1 = (const float*)d_in[6];
    const float* m1 = (const float*)d_in[7];
    const float* v1 = (const float*)d_in[8];
    const float* w2 = (const float*)d_in[9];
    const float* g2 = (const float*)d_in[10];
    const float* b2 = (const float*)d_in[11];
    const float* m2 = (const float*)d_in[12];
    const float* v2 = (const float*)d_in[13];
    (void)in_sizes; (void)n_in; (void)out_size; (void)ws_size;

    // ws layout (total ~50.5 MB << 96 MiB observed ws_size):
    char* ws = (char*)d_ws;
    u16*   wf1   = (u16*)ws;                 // 110,592 B
    u16*   wf2   = (u16*)(ws + 110592);      //  55,296 B
    float* bias1 = (float*)(ws + 165888);    //     128 B
    float* bias2 = (float*)(ws + 166016);    //     128 B
    u16*   x1    = (u16*)(ws + 166144);      // 50,331,648 B  [2][48][64][128][32] bf16

    wfrag_kernel<<<216, 256, 0, stream>>>(w1, g1, b1, m1, v1, wf1, bias1, 64, 6);
    wfrag_kernel<<<108, 256, 0, stream>>>(w2, g2, b2, m2, v2, wf2, bias2, 32, 3);

    // Both vol regions built in one launch (d_out byte-identical regions; vol r is
    // dead before conv2 r overwrites it). Then per pair: conv1 -> x1 -> conv2.
    vol_build_kernel<<<512, 512, 0, stream>>>(lg, rg, lc, rc, (u16*)d_out);
    for (int r = 0; r < 2; r++) {
        u16* vol = (u16*)d_out + (size_t)r * 50331648;   // [2][48][64][128][64] bf16
        conv1_mfma_kernel<<<6144, 256, 0, stream>>>(vol, wf1, bias1, x1);
        conv2_mfma_kernel<<<6144, 256, 0, stream>>>(x1, wf2, bias2, (float*)d_out, 2 * r);
    }
}